// Round 2
// baseline (185.470 us; speedup 1.0000x reference)
//
#include <hip/hip_runtime.h>
#include <hip/hip_bf16.h>

// Shapes (fixed by the reference)
#define BB 16
#define HH 64
#define WW 64
#define CC 256
#define OH 128
#define OW 128
#define FF 256

typedef __attribute__((ext_vector_type(8))) short bf16x8;
typedef __attribute__((ext_vector_type(4))) float f32x4;

// RNE float -> bf16 bits
__device__ __forceinline__ short f2bf(float x) {
    union { float f; unsigned u; } v; v.f = x;
    unsigned r = v.u + 0x7fffu + ((v.u >> 16) & 1u);
    return (short)(r >> 16);
}

// prep: blocks 0..255 transpose pw [c][f] f32 -> pwt [f][c] bf16;
//       block 256 repacks dw [(r*4+s)*256+c] -> dwb [(r*256+c)*4+s] (f32)
__global__ void prep_kernel(const float* __restrict__ pw, const float* __restrict__ dw,
                            short* __restrict__ pwt, float* __restrict__ dwb) {
    if (blockIdx.x < 256) {
        int f = blockIdx.x, c = threadIdx.x;
        pwt[f * CC + c] = f2bf(pw[c * FF + f]);
    } else {
        for (int k = threadIdx.x; k < 4 * 4 * CC; k += 256) {
            int r = k >> 10;
            int rem = k & 1023;
            int s = rem >> 8;
            int c = rem & 255;
            dwb[(r * CC + c) * 4 + s] = dw[(r * 4 + s) * CC + c];
        }
    }
}

__device__ __forceinline__ void tap(float acc[8], const float w[8], const float* xptr) {
    const float4* xp = reinterpret_cast<const float4*>(xptr);
    float4 x0 = xp[0], x1 = xp[1];
    acc[0] += w[0] * x0.x; acc[1] += w[1] * x0.y;
    acc[2] += w[2] * x0.z; acc[3] += w[3] * x0.w;
    acc[4] += w[4] * x1.x; acc[5] += w[5] * x1.y;
    acc[6] += w[6] * x1.z; acc[7] += w[7] * x1.w;
}

// One block = one (b, oh, half-of-ow): 64 output cols x 256 f. 256 threads, 4 waves.
__global__ __launch_bounds__(256, 4)
void sepconvt_kernel(const float* __restrict__ X,
                     const float* __restrict__ dwb,
                     const short* __restrict__ pwt,
                     const float* __restrict__ bias,
                     float* __restrict__ out) {
    __shared__ bf16x8 t_lds[64 * 32];   // 32 KiB: depthwise result (bf16), swizzled

    const int tid = threadIdx.x;
    const int blk = blockIdx.x;         // ((b*OH)+oh)*2 + hw
    const int hw = blk & 1;
    const int oh = (blk >> 1) & (OH - 1);
    const int b  = blk >> 8;

    // Row taps: even oh -> (r=1, i=oh/2), (r=3, i=oh/2-1); odd -> (r=0,(oh+1)/2),(r=2,(oh-1)/2)
    int r0, r1, i0, i1;
    if (oh & 1) { r0 = 0; i0 = (oh + 1) >> 1; r1 = 2; i1 = (oh - 1) >> 1; }
    else        { r0 = 1; i0 = oh >> 1;       r1 = 3; i1 = (oh >> 1) - 1; }

    // ---- Phase 2 B-prefetch (independent of LDS; issues before/during phase 1) ----
    const int lane = tid & 63;
    const int wid  = tid >> 6;        // 4 waves, each owns 64 f columns
    const int lr   = lane & 15;
    const int lk8  = lane >> 4;       // k-subgroup 0..3
    const bf16x8* pwt_v = reinterpret_cast<const bf16x8*>(pwt);
    bf16x8 bpre[4];
    #pragma unroll
    for (int ni = 0; ni < 4; ++ni)
        bpre[ni] = pwt_v[(wid * 64 + ni * 16 + lr) * 32 + lk8];   // kk = 0

    // ---- Phase 1: depthwise transposed conv -> t_lds (bf16) ----
    {
        const int cg  = tid & 31;        // 8-channel group
        const int c0  = cg << 3;
        const int owp = tid >> 5;        // 0..7; ow parity fixed (stride 8)
        const int par = owp & 1;

        // Weights: dwb[(r*256+c)*4 + s] -> float4 of s=0..3 for (r,c).
        // even ow uses s={1,3}; odd ow uses s={0,2}.
        float w[2][2][8];
        const float4* dwb4 = reinterpret_cast<const float4*>(dwb);
        #pragma unroll
        for (int e = 0; e < 8; ++e) {
            float4 wa = dwb4[r0 * CC + c0 + e];
            float4 wb = dwb4[r1 * CC + c0 + e];
            w[0][0][e] = par ? wa.x : wa.y;   // s = se
            w[0][1][e] = par ? wa.z : wa.w;   // s = so
            w[1][0][e] = par ? wb.x : wb.y;
            w[1][1][e] = par ? wb.z : wb.w;
        }

        const bool va0 = (unsigned)i0 < HH;
        const bool va1 = (unsigned)i1 < HH;
        const float* Xr0 = X + (size_t)(b * HH + (va0 ? i0 : 0)) * WW * CC;
        const float* Xr1 = X + (size_t)(b * HH + (va1 ? i1 : 0)) * WW * CC;

        #pragma unroll
        for (int t = 0; t < 8; ++t) {
            const int owl = owp + t * 8;        // local 0..63
            const int ow  = hw * 64 + owl;      // global output col
            int je, jo;
            if (par) { je = (ow + 1) >> 1; jo = (ow - 1) >> 1; }
            else     { je = ow >> 1;       jo = (ow >> 1) - 1; }
            const bool vje = (unsigned)je < WW;
            const bool vjo = (unsigned)jo < WW;

            float acc[8];
            #pragma unroll
            for (int e = 0; e < 8; ++e) acc[e] = 0.f;

            if (va0) {
                if (vje) tap(acc, w[0][0], Xr0 + je * CC + c0);
                if (vjo) tap(acc, w[0][1], Xr0 + jo * CC + c0);
            }
            if (va1) {
                if (vje) tap(acc, w[1][0], Xr1 + je * CC + c0);
                if (vjo) tap(acc, w[1][1], Xr1 + jo * CC + c0);
            }

            bf16x8 tv;
            #pragma unroll
            for (int e = 0; e < 8; ++e) tv[e] = f2bf(acc[e]);
            t_lds[owl * 32 + (cg ^ (owl & 7))] = tv;
        }
    }
    __syncthreads();

    // ---- Phase 2: pointwise GEMM via MFMA (M=64 rows, each wave N=64) ----
    f32x4 acc[4][4];
    #pragma unroll
    for (int mi = 0; mi < 4; ++mi)
        #pragma unroll
        for (int ni = 0; ni < 4; ++ni)
            acc[mi][ni] = (f32x4){0.f, 0.f, 0.f, 0.f};

    #pragma unroll
    for (int kk = 0; kk < 8; ++kk) {            // K = 256, 32 per mfma
        const int kg = kk * 4 + lk8;            // 16B group index along K
        bf16x8 af[4], bfr[4];
        #pragma unroll
        for (int mi = 0; mi < 4; ++mi)
            af[mi] = t_lds[(mi * 16 + lr) * 32 + (kg ^ (lr & 7))];
        if (kk == 0) {
            #pragma unroll
            for (int ni = 0; ni < 4; ++ni) bfr[ni] = bpre[ni];
        } else {
            #pragma unroll
            for (int ni = 0; ni < 4; ++ni)
                bfr[ni] = pwt_v[(wid * 64 + ni * 16 + lr) * 32 + kg];
        }
        #pragma unroll
        for (int mi = 0; mi < 4; ++mi)
            #pragma unroll
            for (int ni = 0; ni < 4; ++ni)
                acc[mi][ni] = __builtin_amdgcn_mfma_f32_16x16x32_bf16(
                    af[mi], bfr[ni], acc[mi][ni], 0, 0, 0);
    }

    // ---- Epilogue: bias + relu + store ----
    float* orow = out + ((size_t)(b * OH + oh) * OW + hw * 64) * FF;
    const int q0 = lk8 * 4;
    #pragma unroll
    for (int ni = 0; ni < 4; ++ni) {
        const int f = wid * 64 + ni * 16 + lr;
        const float bv = bias[f];
        #pragma unroll
        for (int mi = 0; mi < 4; ++mi) {
            const int m = mi * 16 + q0;
            #pragma unroll
            for (int q = 0; q < 4; ++q) {
                float v = acc[mi][ni][q] + bv;
                orow[(size_t)(m + q) * FF + f] = v > 0.f ? v : 0.f;
            }
        }
    }
}

extern "C" void kernel_launch(void* const* d_in, const int* in_sizes, int n_in,
                              void* d_out, int out_size, void* d_ws, size_t ws_size,
                              hipStream_t stream) {
    (void)in_sizes; (void)n_in; (void)out_size; (void)ws_size;
    const float* X    = (const float*)d_in[0];
    const float* dw   = (const float*)d_in[1];
    const float* pw   = (const float*)d_in[2];
    const float* bias = (const float*)d_in[3];
    float* out = (float*)d_out;
    short* pwt = (short*)d_ws;                        // 256*256*2 = 128 KiB
    float* dwb = (float*)((char*)d_ws + 131072);      // 4*256*4*4 = 16 KiB

    prep_kernel<<<dim3(257), dim3(256), 0, stream>>>(pw, dw, pwt, dwb);
    sepconvt_kernel<<<dim3(BB * OH * 2), dim3(256), 0, stream>>>(X, dwb, pwt, bias, out);
}